// Round 4
// baseline (13494.852 us; speedup 1.0000x reference)
//
#include <hip/hip_runtime.h>
#include <hip/hip_bf16.h>
#include <math.h>

// ---- problem constants (from reference) ----
#define DIM    1280
#define HEADS  8
#define DH     160            // DIM / HEADS
#define FRAMES 16
#define BATCH  2
#define TOK    256
#define ESEQ   77
#define INNER  5120           // 4*DIM
#define CROSS  768
#define BF     (BATCH*FRAMES) // 32
#define ROWS   (BF*TOK)       // 8192
#define EROWS  (BF*ESEQ)      // 2464

typedef __hip_bfloat16 bf16;

__device__ __forceinline__ float us2f(unsigned short u) {
    union { float f; unsigned int i; } c; c.i = ((unsigned int)u) << 16; return c.f;
}
__device__ __forceinline__ float b2f(bf16 x) { return __bfloat162float(x); }
__device__ __forceinline__ bf16  f2b(float x) { return __float2bfloat16(x); }

// generic 4-element loaders into f32
__device__ __forceinline__ void load4(const float* p, float* d) {
    float4 v = *(const float4*)p; d[0] = v.x; d[1] = v.y; d[2] = v.z; d[3] = v.w;
}
__device__ __forceinline__ void load4(const bf16* p, float* d) {
    ushort4 v = *(const ushort4*)p; d[0] = us2f(v.x); d[1] = us2f(v.y); d[2] = us2f(v.z); d[3] = us2f(v.w);
}
__device__ __forceinline__ float ldval(const float* p) { return *p; }
__device__ __forceinline__ float ldval(const bf16* p) { return b2f(*p); }
__device__ __forceinline__ void stval(float* p, float v) { *p = v; }
__device__ __forceinline__ void stval(bf16* p, float v) { *p = f2b(v); }

// ---- LayerNorm: one block per row of DIM=1280 (256 thr x 5 elems) ----
template <typename TX>
__global__ __launch_bounds__(256) void ln_kernel(const TX* __restrict__ x,
                                                 const float* __restrict__ w,
                                                 const float* __restrict__ b,
                                                 bf16* __restrict__ out) {
    __shared__ float r1[256], r2[256];
    int row = blockIdx.x, t = threadIdx.x;
    const TX* xp = x + (size_t)row * DIM;
    float v[5], s = 0.f, s2 = 0.f;
#pragma unroll
    for (int i = 0; i < 5; i++) {
        float xv = ldval(xp + t + 256 * i);
        v[i] = xv; s += xv; s2 += xv * xv;
    }
    r1[t] = s; r2[t] = s2; __syncthreads();
    for (int st = 128; st > 0; st >>= 1) {
        if (t < st) { r1[t] += r1[t + st]; r2[t] += r2[t + st]; }
        __syncthreads();
    }
    float mean = r1[0] * (1.f / DIM);
    float var  = r2[0] * (1.f / DIM) - mean * mean;
    float rstd = rsqrtf(var + 1e-5f);
    bf16* op = out + (size_t)row * DIM;
#pragma unroll
    for (int i = 0; i < 5; i++) {
        int c = t + 256 * i;
        op[c] = f2b((v[i] - mean) * rstd * w[c] + b[c]);
    }
}

// ---- generic tiled GEMM: C[M,N](TC) = A[M,K](TA) @ B[K,N](f32) (+bias f32)(+res TR) ----
template <typename TA, typename TC, typename TR>
__global__ __launch_bounds__(256) void gemm_kernel(
    const TA* __restrict__ A, int lda,
    const float* __restrict__ B, int ldb,
    TC* __restrict__ C, int ldc,
    const float* __restrict__ bias,
    const TR* __restrict__ res, int ldres,
    int M, int N, int K) {
    __shared__ float As[16][65];
    __shared__ float Bs[16][65];
    const int t  = threadIdx.x;
    const int m0 = blockIdx.y * 64, n0 = blockIdx.x * 64;
    const int ar = t >> 2, ak = (t & 3) * 4;   // A: 64 rows x 16 k
    const int bk = t >> 4, bn = (t & 15) * 4;  // B: 16 k x 64 n
    const int ty = t >> 4, tx = t & 15;
    float acc[4][4];
#pragma unroll
    for (int i = 0; i < 4; i++)
#pragma unroll
        for (int j = 0; j < 4; j++) acc[i][j] = 0.f;

    for (int k0 = 0; k0 < K; k0 += 16) {
        {
            int m = m0 + ar;
            float tmp[4];
            if (m < M) {
                load4(A + (size_t)m * lda + k0 + ak, tmp);
            } else { tmp[0] = tmp[1] = tmp[2] = tmp[3] = 0.f; }
            As[ak + 0][ar] = tmp[0]; As[ak + 1][ar] = tmp[1];
            As[ak + 2][ar] = tmp[2]; As[ak + 3][ar] = tmp[3];
        }
        {
            float tmp[4];
            load4(B + (size_t)(k0 + bk) * ldb + n0 + bn, tmp);
            Bs[bk][bn + 0] = tmp[0]; Bs[bk][bn + 1] = tmp[1];
            Bs[bk][bn + 2] = tmp[2]; Bs[bk][bn + 3] = tmp[3];
        }
        __syncthreads();
#pragma unroll
        for (int k = 0; k < 16; k++) {
            float a[4], b[4];
#pragma unroll
            for (int i = 0; i < 4; i++) a[i] = As[k][ty * 4 + i];
#pragma unroll
            for (int j = 0; j < 4; j++) b[j] = Bs[k][tx * 4 + j];
#pragma unroll
            for (int i = 0; i < 4; i++)
#pragma unroll
                for (int j = 0; j < 4; j++) acc[i][j] += a[i] * b[j];
        }
        __syncthreads();
    }
#pragma unroll
    for (int i = 0; i < 4; i++) {
        int m = m0 + ty * 4 + i;
        if (m >= M) continue;
#pragma unroll
        for (int j = 0; j < 4; j++) {
            int n = n0 + tx * 4 + j;
            float val = acc[i][j];
            if (bias) val += bias[n];
            if (res)  val += ldval(res + (size_t)m * ldres + n);
            stval(C + (size_t)m * ldc + n, val);
        }
    }
}

// ---- FFN1 fused geglu: P = (A@W[:, :INNER]+b_p) * gelu(A@W[:, INNER:]+b_g) ----
__global__ __launch_bounds__(256) void ffn1_kernel(
    const bf16* __restrict__ A,        // [ROWS, DIM]
    const float* __restrict__ W,       // [DIM, 2*INNER]
    const float* __restrict__ bias,    // [2*INNER]
    bf16* __restrict__ P) {            // [ROWS, INNER]
    __shared__ float As[16][65];
    __shared__ float Bp[16][65];
    __shared__ float Bg[16][65];
    const int t  = threadIdx.x;
    const int m0 = blockIdx.y * 64, n0 = blockIdx.x * 64;
    const int ar = t >> 2, ak = (t & 3) * 4;
    const int bk = t >> 4, bn = (t & 15) * 4;
    const int ty = t >> 4, tx = t & 15;
    float accp[4][4], accg[4][4];
#pragma unroll
    for (int i = 0; i < 4; i++)
#pragma unroll
        for (int j = 0; j < 4; j++) { accp[i][j] = 0.f; accg[i][j] = 0.f; }

    for (int k0 = 0; k0 < DIM; k0 += 16) {
        {
            float tmp[4];
            load4(A + (size_t)(m0 + ar) * DIM + k0 + ak, tmp);
            As[ak + 0][ar] = tmp[0]; As[ak + 1][ar] = tmp[1];
            As[ak + 2][ar] = tmp[2]; As[ak + 3][ar] = tmp[3];
        }
        {
            const float* bp = W + (size_t)(k0 + bk) * (2 * INNER) + n0 + bn;
            float4 pv = *(const float4*)bp;
            float4 gv = *(const float4*)(bp + INNER);
            Bp[bk][bn + 0] = pv.x; Bp[bk][bn + 1] = pv.y;
            Bp[bk][bn + 2] = pv.z; Bp[bk][bn + 3] = pv.w;
            Bg[bk][bn + 0] = gv.x; Bg[bk][bn + 1] = gv.y;
            Bg[bk][bn + 2] = gv.z; Bg[bk][bn + 3] = gv.w;
        }
        __syncthreads();
#pragma unroll
        for (int k = 0; k < 16; k++) {
            float a[4], bp[4], bg[4];
#pragma unroll
            for (int i = 0; i < 4; i++) a[i] = As[k][ty * 4 + i];
#pragma unroll
            for (int j = 0; j < 4; j++) { bp[j] = Bp[k][tx * 4 + j]; bg[j] = Bg[k][tx * 4 + j]; }
#pragma unroll
            for (int i = 0; i < 4; i++)
#pragma unroll
                for (int j = 0; j < 4; j++) {
                    accp[i][j] += a[i] * bp[j];
                    accg[i][j] += a[i] * bg[j];
                }
        }
        __syncthreads();
    }
#pragma unroll
    for (int i = 0; i < 4; i++) {
        int m = m0 + ty * 4 + i;
#pragma unroll
        for (int j = 0; j < 4; j++) {
            int n = n0 + tx * 4 + j;
            float p = accp[i][j] + bias[n];
            float g = accg[i][j] + bias[INNER + n];
            float gl = 0.5f * g * (1.f + erff(g * 0.70710678118654752f));
            P[(size_t)m * INNER + n] = f2b(p * gl);
        }
    }
}

#define SOFTMAX_SCALE 0.07905694150420949f  // 1/sqrt(160)

// ---- attn1: sparse-causal self-attn, 512 keys (frame0 ++ former frame) ----
__global__ __launch_bounds__(256) void attn1_kernel(const bf16* __restrict__ q,
                                                    const bf16* __restrict__ k,
                                                    const bf16* __restrict__ v,
                                                    bf16* __restrict__ o) {
    __shared__ float sQ[DH];
    __shared__ float sS[512];
    __shared__ float red[256];
    int t = threadIdx.x;
    int qi = blockIdx.x, hd = blockIdx.y, bfi = blockIdx.z;
    int bi = bfi >> 4, fi = bfi & 15;
    int former = fi > 0 ? fi - 1 : 0;
    size_t qbase = ((size_t)(bfi * TOK + qi)) * DIM + hd * DH;
    if (t < DH) sQ[t] = b2f(q[qbase + t]);
    __syncthreads();
    for (int j = t; j < 512; j += 256) {
        int kf = (j < 256) ? 0 : former;
        int jj = j & 255;
        size_t kbase = ((size_t)((bi * FRAMES + kf) * TOK + jj)) * DIM + hd * DH;
        float acc = 0.f;
        for (int d = 0; d < DH; d++) acc += sQ[d] * b2f(k[kbase + d]);
        sS[j] = acc * SOFTMAX_SCALE;
    }
    __syncthreads();
    float lm = -1e30f;
    for (int j = t; j < 512; j += 256) lm = fmaxf(lm, sS[j]);
    red[t] = lm; __syncthreads();
    for (int s = 128; s > 0; s >>= 1) { if (t < s) red[t] = fmaxf(red[t], red[t + s]); __syncthreads(); }
    float mx = red[0]; __syncthreads();
    float ls = 0.f;
    for (int j = t; j < 512; j += 256) { float e = __expf(sS[j] - mx); sS[j] = e; ls += e; }
    red[t] = ls; __syncthreads();
    for (int s = 128; s > 0; s >>= 1) { if (t < s) red[t] += red[t + s]; __syncthreads(); }
    float inv = 1.f / red[0];
    __syncthreads();
    if (t < DH) {
        float acc = 0.f;
        for (int j = 0; j < 512; j++) {
            int kf = (j < 256) ? 0 : former;
            int jj = j & 255;
            size_t vbase = ((size_t)((bi * FRAMES + kf) * TOK + jj)) * DIM + hd * DH;
            acc += sS[j] * b2f(v[vbase + t]);
        }
        o[qbase + t] = f2b(acc * inv);
    }
}

// ---- attn2: cross-attention, 77 keys ----
__global__ __launch_bounds__(256) void attn2_kernel(const bf16* __restrict__ q,
                                                    const bf16* __restrict__ k,
                                                    const bf16* __restrict__ v,
                                                    bf16* __restrict__ o) {
    __shared__ float sQ[DH];
    __shared__ float sS[128];
    __shared__ float red[256];
    int t = threadIdx.x;
    int qi = blockIdx.x, hd = blockIdx.y, bfi = blockIdx.z;
    size_t qbase = ((size_t)(bfi * TOK + qi)) * DIM + hd * DH;
    if (t < DH) sQ[t] = b2f(q[qbase + t]);
    __syncthreads();
    if (t < ESEQ) {
        size_t kbase = ((size_t)(bfi * ESEQ + t)) * DIM + hd * DH;
        float acc = 0.f;
        for (int d = 0; d < DH; d++) acc += sQ[d] * b2f(k[kbase + d]);
        sS[t] = acc * SOFTMAX_SCALE;
    }
    __syncthreads();
    float lm = (t < ESEQ) ? sS[t] : -1e30f;
    red[t] = lm; __syncthreads();
    for (int s = 128; s > 0; s >>= 1) { if (t < s) red[t] = fmaxf(red[t], red[t + s]); __syncthreads(); }
    float mx = red[0]; __syncthreads();
    float ls = 0.f;
    if (t < ESEQ) { float e = __expf(sS[t] - mx); sS[t] = e; ls = e; }
    red[t] = ls; __syncthreads();
    for (int s = 128; s > 0; s >>= 1) { if (t < s) red[t] += red[t + s]; __syncthreads(); }
    float inv = 1.f / red[0];
    __syncthreads();
    if (t < DH) {
        float acc = 0.f;
        for (int j = 0; j < ESEQ; j++) {
            size_t vbase = ((size_t)(bfi * ESEQ + j)) * DIM + hd * DH;
            acc += sS[j] * b2f(v[vbase + t]);
        }
        o[qbase + t] = f2b(acc * inv);
    }
}

// ---- temporal self-attn: 16 keys (frames) per (batch, token) ----
__global__ __launch_bounds__(256) void attnt_kernel(const bf16* __restrict__ q,
                                                    const bf16* __restrict__ k,
                                                    const bf16* __restrict__ v,
                                                    bf16* __restrict__ o) {
    __shared__ float sQ[DH];
    __shared__ float sS[16];
    __shared__ float red[256];
    int t = threadIdx.x;
    int qfi = blockIdx.x, hd = blockIdx.y, z = blockIdx.z;
    int bi = z >> 8, ti = z & 255;
    size_t qbase = ((size_t)((bi * FRAMES + qfi) * TOK + ti)) * DIM + hd * DH;
    if (t < DH) sQ[t] = b2f(q[qbase + t]);
    __syncthreads();
    if (t < FRAMES) {
        size_t kbase = ((size_t)((bi * FRAMES + t) * TOK + ti)) * DIM + hd * DH;
        float acc = 0.f;
        for (int d = 0; d < DH; d++) acc += sQ[d] * b2f(k[kbase + d]);
        sS[t] = acc * SOFTMAX_SCALE;
    }
    __syncthreads();
    float lm = (t < FRAMES) ? sS[t] : -1e30f;
    red[t] = lm; __syncthreads();
    for (int s = 128; s > 0; s >>= 1) { if (t < s) red[t] = fmaxf(red[t], red[t + s]); __syncthreads(); }
    float mx = red[0]; __syncthreads();
    float ls = 0.f;
    if (t < FRAMES) { float e = __expf(sS[t] - mx); sS[t] = e; ls = e; }
    red[t] = ls; __syncthreads();
    for (int s = 128; s > 0; s >>= 1) { if (t < s) red[t] += red[t + s]; __syncthreads(); }
    float inv = 1.f / red[0];
    __syncthreads();
    if (t < DH) {
        float acc = 0.f;
        for (int j = 0; j < FRAMES; j++) {
            size_t vbase = ((size_t)((bi * FRAMES + j) * TOK + ti)) * DIM + hd * DH;
            acc += sS[j] * b2f(v[vbase + t]);
        }
        o[qbase + t] = f2b(acc * inv);
    }
}

extern "C" void kernel_launch(void* const* d_in, const int* in_sizes, int n_in,
                              void* d_out, int out_size, void* d_ws, size_t ws_size,
                              hipStream_t stream) {
    (void)in_sizes; (void)n_in; (void)out_size; (void)ws_size;
    const float* hs   = (const float*)d_in[0];
    const float* enc  = (const float*)d_in[1];
    const float* n1w  = (const float*)d_in[2];
    const float* n1b  = (const float*)d_in[3];
    const float* a1wq = (const float*)d_in[4];
    const float* a1wk = (const float*)d_in[5];
    const float* a1wv = (const float*)d_in[6];
    const float* a1wo = (const float*)d_in[7];
    const float* a1bo = (const float*)d_in[8];
    const float* n2w  = (const float*)d_in[9];
    const float* n2b  = (const float*)d_in[10];
    const float* a2wq = (const float*)d_in[11];
    const float* a2wk = (const float*)d_in[12];
    const float* a2wv = (const float*)d_in[13];
    const float* a2wo = (const float*)d_in[14];
    const float* a2bo = (const float*)d_in[15];
    const float* n3w  = (const float*)d_in[16];
    const float* n3b  = (const float*)d_in[17];
    const float* ffw1 = (const float*)d_in[18];
    const float* ffb1 = (const float*)d_in[19];
    const float* ffw2 = (const float*)d_in[20];
    const float* ffb2 = (const float*)d_in[21];
    const float* ntw  = (const float*)d_in[22];
    const float* ntb  = (const float*)d_in[23];
    const float* atwq = (const float*)d_in[24];
    const float* atwk = (const float*)d_in[25];
    const float* atwv = (const float*)d_in[26];
    const float* atwo = (const float*)d_in[27];
    const float* atbo = (const float*)d_in[28];

    // ---- workspace carve: 105 MB total (proven to fit) ----
    char* wp = (char*)d_ws;
    auto carve = [&](size_t bytes) -> char* {
        char* p = wp; wp += (bytes + 255) & ~((size_t)255); return p;
    };
    bf16* nh = (bf16*)carve((size_t)ROWS * DIM * 2);
    bf16* qb = (bf16*)carve((size_t)ROWS * DIM * 2);
    bf16* kb = (bf16*)carve((size_t)ROWS * DIM * 2);
    bf16* vb = (bf16*)carve((size_t)ROWS * DIM * 2);
    bf16* ob = (bf16*)carve((size_t)ROWS * DIM * 2);
    bf16* Pb = qb;  // FFN intermediate aliases qb..ob (exactly ROWS*INNER*2 bytes)
    float* out = (float*)d_out;   // f32 residual stream lives in d_out

    dim3 blk(256);
    // internal projection: bf16 A -> bf16 C, no residual
    auto gemmB = [&](const bf16* A, int lda, const float* B, int ldb,
                     bf16* C, int ldc, int M, int N, int K) {
        dim3 grid(N / 64, (M + 63) / 64);
        gemm_kernel<bf16, bf16, bf16><<<grid, blk, 0, stream>>>(
            A, lda, B, ldb, C, ldc, nullptr, (const bf16*)nullptr, 0, M, N, K);
    };
    // f32 A -> bf16 C (encoder projections)
    auto gemmF = [&](const float* A, int lda, const float* B, int ldb,
                     bf16* C, int ldc, int M, int N, int K) {
        dim3 grid(N / 64, (M + 63) / 64);
        gemm_kernel<float, bf16, bf16><<<grid, blk, 0, stream>>>(
            A, lda, B, ldb, C, ldc, nullptr, (const bf16*)nullptr, 0, M, N, K);
    };
    // out-projection: bf16 A -> f32 C(out) + bias + f32 residual
    auto gemmO = [&](const bf16* A, int lda, const float* B,
                     const float* bias, const float* res, int M, int K) {
        dim3 grid(DIM / 64, M / 64);
        gemm_kernel<bf16, float, float><<<grid, blk, 0, stream>>>(
            A, lda, B, DIM, out, DIM, bias, res, DIM, M, DIM, K);
    };

    // ---- attn1: sparse-causal self-attention ----
    ln_kernel<float><<<dim3(ROWS), blk, 0, stream>>>(hs, n1w, n1b, nh);
    gemmB(nh, DIM, a1wq, DIM, qb, DIM, ROWS, DIM, DIM);
    gemmB(nh, DIM, a1wk, DIM, kb, DIM, ROWS, DIM, DIM);
    gemmB(nh, DIM, a1wv, DIM, vb, DIM, ROWS, DIM, DIM);
    attn1_kernel<<<dim3(TOK, HEADS, BF), blk, 0, stream>>>(qb, kb, vb, ob);
    gemmO(ob, DIM, a1wo, a1bo, hs, ROWS, DIM);          // out = ob@a1wo + a1bo + hs

    // ---- attn2: cross-attention ----
    ln_kernel<float><<<dim3(ROWS), blk, 0, stream>>>(out, n2w, n2b, nh);
    gemmB(nh, DIM, a2wq, DIM, qb, DIM, ROWS, DIM, DIM);
    gemmF(enc, CROSS, a2wk, DIM, kb, DIM, EROWS, DIM, CROSS);
    gemmF(enc, CROSS, a2wv, DIM, vb, DIM, EROWS, DIM, CROSS);
    attn2_kernel<<<dim3(TOK, HEADS, BF), blk, 0, stream>>>(qb, kb, vb, ob);
    gemmO(ob, DIM, a2wo, a2bo, out, ROWS, DIM);         // out += ob@a2wo + a2bo

    // ---- geglu FFN ----
    ln_kernel<float><<<dim3(ROWS), blk, 0, stream>>>(out, n3w, n3b, nh);
    ffn1_kernel<<<dim3(INNER / 64, ROWS / 64), blk, 0, stream>>>(nh, ffw1, ffb1, Pb);
    gemmO(Pb, INNER, ffw2, ffb2, out, ROWS, INNER);     // out += P@ffw2 + ffb2

    // ---- temporal self-attention ----
    ln_kernel<float><<<dim3(ROWS), blk, 0, stream>>>(out, ntw, ntb, nh);
    gemmB(nh, DIM, atwq, DIM, qb, DIM, ROWS, DIM, DIM);
    gemmB(nh, DIM, atwk, DIM, kb, DIM, ROWS, DIM, DIM);
    gemmB(nh, DIM, atwv, DIM, vb, DIM, ROWS, DIM, DIM);
    attnt_kernel<<<dim3(FRAMES, HEADS, BATCH * TOK), blk, 0, stream>>>(qb, kb, vb, ob);
    gemmO(ob, DIM, atwo, atbo, out, ROWS, DIM);         // out += ob@atwo + atbo
}

// Round 5
// 5223.376 us; speedup vs baseline: 2.5835x; 2.5835x over previous
//
#include <hip/hip_runtime.h>
#include <hip/hip_bf16.h>
#include <math.h>

// ---- problem constants (from reference) ----
#define DIM    1280
#define HEADS  8
#define DH     160            // DIM / HEADS
#define FRAMES 16
#define BATCH  2
#define TOK    256
#define ESEQ   77
#define INNER  5120           // 4*DIM
#define CROSS  768
#define BF     (BATCH*FRAMES) // 32
#define ROWS   (BF*TOK)       // 8192
#define EROWS  (BF*ESEQ)      // 2464

typedef __hip_bfloat16 bf16;
typedef __attribute__((ext_vector_type(8))) short s8v;
typedef __attribute__((ext_vector_type(4))) short s4v;
typedef __attribute__((ext_vector_type(4))) float f4v;

__device__ __forceinline__ float us2f(unsigned short u) {
    union { float f; unsigned int i; } c; c.i = ((unsigned int)u) << 16; return c.f;
}
__device__ __forceinline__ float b2f(bf16 x) { return __bfloat162float(x); }
__device__ __forceinline__ bf16  f2b(float x) { return __float2bfloat16(x); }
// f32 -> bf16 bits (RNE), as short
__device__ __forceinline__ short f2s(float x) {
    union { float f; unsigned int u; } c; c.f = x;
    unsigned int r = c.u + 0x7FFF + ((c.u >> 16) & 1);
    return (short)(r >> 16);
}

__device__ __forceinline__ void load4(const float* p, float* d) {
    float4 v = *(const float4*)p; d[0] = v.x; d[1] = v.y; d[2] = v.z; d[3] = v.w;
}
__device__ __forceinline__ float ldval(const float* p) { return *p; }
__device__ __forceinline__ float ldval(const bf16* p) { return b2f(*p); }

// ---- LayerNorm: one block per row of DIM=1280 (256 thr x 5 elems) ----
__global__ __launch_bounds__(256) void ln_kernel(const float* __restrict__ x,
                                                 const float* __restrict__ w,
                                                 const float* __restrict__ b,
                                                 bf16* __restrict__ out) {
    __shared__ float r1[256], r2[256];
    int row = blockIdx.x, t = threadIdx.x;
    const float* xp = x + (size_t)row * DIM;
    float v[5], s = 0.f, s2 = 0.f;
#pragma unroll
    for (int i = 0; i < 5; i++) {
        float xv = xp[t + 256 * i];
        v[i] = xv; s += xv; s2 += xv * xv;
    }
    r1[t] = s; r2[t] = s2; __syncthreads();
    for (int st = 128; st > 0; st >>= 1) {
        if (t < st) { r1[t] += r1[t + st]; r2[t] += r2[t + st]; }
        __syncthreads();
    }
    float mean = r1[0] * (1.f / DIM);
    float var  = r2[0] * (1.f / DIM) - mean * mean;
    float rstd = rsqrtf(var + 1e-5f);
    bf16* op = out + (size_t)row * DIM;
#pragma unroll
    for (int i = 0; i < 5; i++) {
        int c = t + 256 * i;
        op[c] = f2b((v[i] - mean) * rstd * w[c] + b[c]);
    }
}

// =====================================================================
// MFMA GEMM: C[M,N] = A[M,K](bf16) @ B[K,N](f32 weights)
// 128x128 block tile, BK=32, mfma_f32_16x16x32_bf16, 4 waves (each 64x64).
// EPI: 0 = bf16 out, no bias
//      1 = f32 out = acc + bias[n] + res[m] (residual stream)
//      2 = geglu: bf16 out = (accP+bias[n]) * gelu(accG+bias[INNER+n]),
//          G strip at B+INNER (ldb = 2*INNER)
// Requires M%128==0, N%128==0, K%32==0.
// =====================================================================
template <int EPI>
__global__ __launch_bounds__(256) void gemm_mfma(
    const bf16* __restrict__ A, int lda,
    const float* __restrict__ B, int ldb,
    void* __restrict__ C, int ldc,
    const float* __restrict__ bias,
    const float* __restrict__ res, int ldres,
    int M, int N, int K) {
    constexpr int LR = 40;                       // LDS row pitch in shorts (32 + 8 pad, 16B-aligned)
    __shared__ short A_lds[128 * LR];
    __shared__ short B_lds[128 * LR];
    __shared__ short G_lds[EPI == 2 ? 128 * LR : 4];

    const int t    = threadIdx.x;
    const int wid  = t >> 6, lane = t & 63;
    const int lrow = lane & 15, lgrp = lane >> 4;
    const int m0   = blockIdx.y * 128, n0 = blockIdx.x * 128;
    const int wm   = (wid & 1) * 64, wn = (wid >> 1) * 64;

    f4v acc[4][4];
    f4v accg[4][4];
#pragma unroll
    for (int i = 0; i < 4; i++)
#pragma unroll
        for (int j = 0; j < 4; j++) {
            acc[i][j] = (f4v){0.f, 0.f, 0.f, 0.f};
            if (EPI == 2) accg[i][j] = (f4v){0.f, 0.f, 0.f, 0.f};
        }

    const int b_np = (t & 31) * 4;   // n patch base (0..124)
    const int b_kp = (t >> 5) * 4;   // k patch base (0..28)

    for (int k0 = 0; k0 < K; k0 += 32) {
        // ---- stage A: 128x32 bf16, 2 chunks of 16B per thread ----
#pragma unroll
        for (int c = 0; c < 2; c++) {
            int idx = t + c * 256;
            int row = idx >> 2, g = (idx & 3) * 8;
            uint4 v = *(const uint4*)(A + (size_t)(m0 + row) * lda + k0 + g);
            *(uint4*)&A_lds[row * LR + g] = v;
        }
        // ---- stage B: 32x128 f32 -> transposed bf16 B_lds[n][k] ----
        {
            const float* bp = B + (size_t)(k0 + b_kp) * ldb + n0 + b_np;
            float4 r0 = *(const float4*)(bp);
            float4 r1 = *(const float4*)(bp + ldb);
            float4 r2 = *(const float4*)(bp + 2 * ldb);
            float4 r3 = *(const float4*)(bp + 3 * ldb);
            *(s4v*)&B_lds[(b_np + 0) * LR + b_kp] = (s4v){f2s(r0.x), f2s(r1.x), f2s(r2.x), f2s(r3.x)};
            *(s4v*)&B_lds[(b_np + 1) * LR + b_kp] = (s4v){f2s(r0.y), f2s(r1.y), f2s(r2.y), f2s(r3.y)};
            *(s4v*)&B_lds[(b_np + 2) * LR + b_kp] = (s4v){f2s(r0.z), f2s(r1.z), f2s(r2.z), f2s(r3.z)};
            *(s4v*)&B_lds[(b_np + 3) * LR + b_kp] = (s4v){f2s(r0.w), f2s(r1.w), f2s(r2.w), f2s(r3.w)};
        }
        if (EPI == 2) {
            const float* gp = B + (size_t)(k0 + b_kp) * ldb + INNER + n0 + b_np;
            float4 r0 = *(const float4*)(gp);
            float4 r1 = *(const float4*)(gp + ldb);
            float4 r2 = *(const float4*)(gp + 2 * ldb);
            float4 r3 = *(const float4*)(gp + 3 * ldb);
            *(s4v*)&G_lds[(b_np + 0) * LR + b_kp] = (s4v){f2s(r0.x), f2s(r1.x), f2s(r2.x), f2s(r3.x)};
            *(s4v*)&G_lds[(b_np + 1) * LR + b_kp] = (s4v){f2s(r0.y), f2s(r1.y), f2s(r2.y), f2s(r3.y)};
            *(s4v*)&G_lds[(b_np + 2) * LR + b_kp] = (s4v){f2s(r0.z), f2s(r1.z), f2s(r2.z), f2s(r3.z)};
            *(s4v*)&G_lds[(b_np + 3) * LR + b_kp] = (s4v){f2s(r0.w), f2s(r1.w), f2s(r2.w), f2s(r3.w)};
        }
        __syncthreads();
        // ---- fragments + MFMA ----
        s8v af[4], bfr[4];
#pragma unroll
        for (int i = 0; i < 4; i++)
            af[i] = *(const s8v*)&A_lds[(wm + i * 16 + lrow) * LR + lgrp * 8];
#pragma unroll
        for (int j = 0; j < 4; j++)
            bfr[j] = *(const s8v*)&B_lds[(wn + j * 16 + lrow) * LR + lgrp * 8];
#pragma unroll
        for (int i = 0; i < 4; i++)
#pragma unroll
            for (int j = 0; j < 4; j++)
                acc[i][j] = __builtin_amdgcn_mfma_f32_16x16x32_bf16(af[i], bfr[j], acc[i][j], 0, 0, 0);
        if (EPI == 2) {
            s8v gfr[4];
#pragma unroll
            for (int j = 0; j < 4; j++)
                gfr[j] = *(const s8v*)&G_lds[(wn + j * 16 + lrow) * LR + lgrp * 8];
#pragma unroll
            for (int i = 0; i < 4; i++)
#pragma unroll
                for (int j = 0; j < 4; j++)
                    accg[i][j] = __builtin_amdgcn_mfma_f32_16x16x32_bf16(af[i], gfr[j], accg[i][j], 0, 0, 0);
        }
        __syncthreads();
    }

    // ---- epilogue: C/D layout col=lane&15, row=(lane>>4)*4+reg ----
#pragma unroll
    for (int i = 0; i < 4; i++) {
#pragma unroll
        for (int r = 0; r < 4; r++) {
            int m = m0 + wm + i * 16 + lgrp * 4 + r;
#pragma unroll
            for (int j = 0; j < 4; j++) {
                int n = n0 + wn + j * 16 + lrow;
                float v = acc[i][j][r];
                if (EPI == 0) {
                    ((bf16*)C)[(size_t)m * ldc + n] = f2b(v);
                } else if (EPI == 1) {
                    v += bias[n] + res[(size_t)m * ldres + n];
                    ((float*)C)[(size_t)m * ldc + n] = v;
                } else {
                    float p = v + bias[n];
                    float g = accg[i][j][r] + bias[INNER + n];
                    float gl = 0.5f * g * (1.f + erff(g * 0.70710678118654752f));
                    ((bf16*)C)[(size_t)m * ldc + n] = f2b(p * gl);
                }
            }
        }
    }
}

// ---- old VALU GEMM (used only for encoder projections: M=2464 not %128) ----
__global__ __launch_bounds__(256) void gemm_valu(
    const float* __restrict__ A, int lda,
    const float* __restrict__ B, int ldb,
    bf16* __restrict__ C, int ldc,
    int M, int N, int K) {
    __shared__ float As[16][65];
    __shared__ float Bs[16][65];
    const int t  = threadIdx.x;
    const int m0 = blockIdx.y * 64, n0 = blockIdx.x * 64;
    const int ar = t >> 2, ak = (t & 3) * 4;
    const int bk = t >> 4, bn = (t & 15) * 4;
    const int ty = t >> 4, tx = t & 15;
    float acc[4][4];
#pragma unroll
    for (int i = 0; i < 4; i++)
#pragma unroll
        for (int j = 0; j < 4; j++) acc[i][j] = 0.f;

    for (int k0 = 0; k0 < K; k0 += 16) {
        {
            int m = m0 + ar;
            float tmp[4];
            if (m < M) load4(A + (size_t)m * lda + k0 + ak, tmp);
            else { tmp[0] = tmp[1] = tmp[2] = tmp[3] = 0.f; }
            As[ak + 0][ar] = tmp[0]; As[ak + 1][ar] = tmp[1];
            As[ak + 2][ar] = tmp[2]; As[ak + 3][ar] = tmp[3];
        }
        {
            float tmp[4];
            load4(B + (size_t)(k0 + bk) * ldb + n0 + bn, tmp);
            Bs[bk][bn + 0] = tmp[0]; Bs[bk][bn + 1] = tmp[1];
            Bs[bk][bn + 2] = tmp[2]; Bs[bk][bn + 3] = tmp[3];
        }
        __syncthreads();
#pragma unroll
        for (int k = 0; k < 16; k++) {
            float a[4], b[4];
#pragma unroll
            for (int i = 0; i < 4; i++) a[i] = As[k][ty * 4 + i];
#pragma unroll
            for (int j = 0; j < 4; j++) b[j] = Bs[k][tx * 4 + j];
#pragma unroll
            for (int i = 0; i < 4; i++)
#pragma unroll
                for (int j = 0; j < 4; j++) acc[i][j] += a[i] * b[j];
        }
        __syncthreads();
    }
#pragma unroll
    for (int i = 0; i < 4; i++) {
        int m = m0 + ty * 4 + i;
        if (m >= M) continue;
#pragma unroll
        for (int j = 0; j < 4; j++) {
            int n = n0 + tx * 4 + j;
            C[(size_t)m * ldc + n] = f2b(acc[i][j]);
        }
    }
}

#define SOFTMAX_SCALE 0.07905694150420949f  // 1/sqrt(160)

// ---- attn1: sparse-causal self-attn, 512 keys (frame0 ++ former frame) ----
__global__ __launch_bounds__(256) void attn1_kernel(const bf16* __restrict__ q,
                                                    const bf16* __restrict__ k,
                                                    const bf16* __restrict__ v,
                                                    bf16* __restrict__ o) {
    __shared__ float sQ[DH];
    __shared__ float sS[512];
    __shared__ float red[256];
    int t = threadIdx.x;
    int qi = blockIdx.x, hd = blockIdx.y, bfi = blockIdx.z;
    int bi = bfi >> 4, fi = bfi & 15;
    int former = fi > 0 ? fi - 1 : 0;
    size_t qbase = ((size_t)(bfi * TOK + qi)) * DIM + hd * DH;
    if (t < DH) sQ[t] = b2f(q[qbase + t]);
    __syncthreads();
    for (int j = t; j < 512; j += 256) {
        int kf = (j < 256) ? 0 : former;
        int jj = j & 255;
        size_t kbase = ((size_t)((bi * FRAMES + kf) * TOK + jj)) * DIM + hd * DH;
        float acc = 0.f;
        for (int d = 0; d < DH; d++) acc += sQ[d] * b2f(k[kbase + d]);
        sS[j] = acc * SOFTMAX_SCALE;
    }
    __syncthreads();
    float lm = -1e30f;
    for (int j = t; j < 512; j += 256) lm = fmaxf(lm, sS[j]);
    red[t] = lm; __syncthreads();
    for (int s = 128; s > 0; s >>= 1) { if (t < s) red[t] = fmaxf(red[t], red[t + s]); __syncthreads(); }
    float mx = red[0]; __syncthreads();
    float ls = 0.f;
    for (int j = t; j < 512; j += 256) { float e = __expf(sS[j] - mx); sS[j] = e; ls += e; }
    red[t] = ls; __syncthreads();
    for (int s = 128; s > 0; s >>= 1) { if (t < s) red[t] += red[t + s]; __syncthreads(); }
    float inv = 1.f / red[0];
    __syncthreads();
    if (t < DH) {
        float acc = 0.f;
        for (int j = 0; j < 512; j++) {
            int kf = (j < 256) ? 0 : former;
            int jj = j & 255;
            size_t vbase = ((size_t)((bi * FRAMES + kf) * TOK + jj)) * DIM + hd * DH;
            acc += sS[j] * b2f(v[vbase + t]);
        }
        o[qbase + t] = f2b(acc * inv);
    }
}

// ---- attn2: cross-attention, 77 keys ----
__global__ __launch_bounds__(256) void attn2_kernel(const bf16* __restrict__ q,
                                                    const bf16* __restrict__ k,
                                                    const bf16* __restrict__ v,
                                                    bf16* __restrict__ o) {
    __shared__ float sQ[DH];
    __shared__ float sS[128];
    __shared__ float red[256];
    int t = threadIdx.x;
    int qi = blockIdx.x, hd = blockIdx.y, bfi = blockIdx.z;
    size_t qbase = ((size_t)(bfi * TOK + qi)) * DIM + hd * DH;
    if (t < DH) sQ[t] = b2f(q[qbase + t]);
    __syncthreads();
    if (t < ESEQ) {
        size_t kbase = ((size_t)(bfi * ESEQ + t)) * DIM + hd * DH;
        float acc = 0.f;
        for (int d = 0; d < DH; d++) acc += sQ[d] * b2f(k[kbase + d]);
        sS[t] = acc * SOFTMAX_SCALE;
    }
    __syncthreads();
    float lm = (t < ESEQ) ? sS[t] : -1e30f;
    red[t] = lm; __syncthreads();
    for (int s = 128; s > 0; s >>= 1) { if (t < s) red[t] = fmaxf(red[t], red[t + s]); __syncthreads(); }
    float mx = red[0]; __syncthreads();
    float ls = 0.f;
    if (t < ESEQ) { float e = __expf(sS[t] - mx); sS[t] = e; ls = e; }
    red[t] = ls; __syncthreads();
    for (int s = 128; s > 0; s >>= 1) { if (t < s) red[t] += red[t + s]; __syncthreads(); }
    float inv = 1.f / red[0];
    __syncthreads();
    if (t < DH) {
        float acc = 0.f;
        for (int j = 0; j < ESEQ; j++) {
            size_t vbase = ((size_t)(bfi * ESEQ + j)) * DIM + hd * DH;
            acc += sS[j] * b2f(v[vbase + t]);
        }
        o[qbase + t] = f2b(acc * inv);
    }
}

// ---- temporal self-attn: 16 keys (frames) per (batch, token) ----
__global__ __launch_bounds__(256) void attnt_kernel(const bf16* __restrict__ q,
                                                    const bf16* __restrict__ k,
                                                    const bf16* __restrict__ v,
                                                    bf16* __restrict__ o) {
    __shared__ float sQ[DH];
    __shared__ float sS[16];
    __shared__ float red[256];
    int t = threadIdx.x;
    int qfi = blockIdx.x, hd = blockIdx.y, z = blockIdx.z;
    int bi = z >> 8, ti = z & 255;
    size_t qbase = ((size_t)((bi * FRAMES + qfi) * TOK + ti)) * DIM + hd * DH;
    if (t < DH) sQ[t] = b2f(q[qbase + t]);
    __syncthreads();
    if (t < FRAMES) {
        size_t kbase = ((size_t)((bi * FRAMES + t) * TOK + ti)) * DIM + hd * DH;
        float acc = 0.f;
        for (int d = 0; d < DH; d++) acc += sQ[d] * b2f(k[kbase + d]);
        sS[t] = acc * SOFTMAX_SCALE;
    }
    __syncthreads();
    float lm = (t < FRAMES) ? sS[t] : -1e30f;
    red[t] = lm; __syncthreads();
    for (int s = 128; s > 0; s >>= 1) { if (t < s) red[t] = fmaxf(red[t], red[t + s]); __syncthreads(); }
    float mx = red[0]; __syncthreads();
    float ls = 0.f;
    if (t < FRAMES) { float e = __expf(sS[t] - mx); sS[t] = e; ls = e; }
    red[t] = ls; __syncthreads();
    for (int s = 128; s > 0; s >>= 1) { if (t < s) red[t] += red[t + s]; __syncthreads(); }
    float inv = 1.f / red[0];
    __syncthreads();
    if (t < DH) {
        float acc = 0.f;
        for (int j = 0; j < FRAMES; j++) {
            size_t vbase = ((size_t)((bi * FRAMES + j) * TOK + ti)) * DIM + hd * DH;
            acc += sS[j] * b2f(v[vbase + t]);
        }
        o[qbase + t] = f2b(acc * inv);
    }
}

extern "C" void kernel_launch(void* const* d_in, const int* in_sizes, int n_in,
                              void* d_out, int out_size, void* d_ws, size_t ws_size,
                              hipStream_t stream) {
    (void)in_sizes; (void)n_in; (void)out_size; (void)ws_size;
    const float* hs   = (const float*)d_in[0];
    const float* enc  = (const float*)d_in[1];
    const float* n1w  = (const float*)d_in[2];
    const float* n1b  = (const float*)d_in[3];
    const float* a1wq = (const float*)d_in[4];
    const float* a1wk = (const float*)d_in[5];
    const float* a1wv = (const float*)d_in[6];
    const float* a1wo = (const float*)d_in[7];
    const float* a1bo = (const float*)d_in[8];
    const float* n2w  = (const float*)d_in[9];
    const float* n2b  = (const float*)d_in[10];
    const float* a2wq = (const float*)d_in[11];
    const float* a2wk = (const float*)d_in[12];
    const float* a2wv = (const float*)d_in[13];
    const float* a2wo = (const float*)d_in[14];
    const float* a2bo = (const float*)d_in[15];
    const float* n3w  = (const float*)d_in[16];
    const float* n3b  = (const float*)d_in[17];
    const float* ffw1 = (const float*)d_in[18];
    const float* ffb1 = (const float*)d_in[19];
    const float* ffw2 = (const float*)d_in[20];
    const float* ffb2 = (const float*)d_in[21];
    const float* ntw  = (const float*)d_in[22];
    const float* ntb  = (const float*)d_in[23];
    const float* atwq = (const float*)d_in[24];
    const float* atwk = (const float*)d_in[25];
    const float* atwv = (const float*)d_in[26];
    const float* atwo = (const float*)d_in[27];
    const float* atbo = (const float*)d_in[28];

    // ---- workspace carve: 105 MB total (proven to fit) ----
    char* wp = (char*)d_ws;
    auto carve = [&](size_t bytes) -> char* {
        char* p = wp; wp += (bytes + 255) & ~((size_t)255); return p;
    };
    bf16* nh = (bf16*)carve((size_t)ROWS * DIM * 2);
    bf16* qb = (bf16*)carve((size_t)ROWS * DIM * 2);
    bf16* kb = (bf16*)carve((size_t)ROWS * DIM * 2);
    bf16* vb = (bf16*)carve((size_t)ROWS * DIM * 2);
    bf16* ob = (bf16*)carve((size_t)ROWS * DIM * 2);
    bf16* Pb = qb;  // FFN intermediate aliases qb..ob (exactly ROWS*INNER*2 bytes)
    float* out = (float*)d_out;   // f32 residual stream lives in d_out

    dim3 blk(256);
    // bf16 A -> bf16 C projection
    auto proj = [&](const bf16* A, int lda, const float* B, int ldb,
                    bf16* C, int ldc, int M, int N, int K) {
        gemm_mfma<0><<<dim3(N / 128, M / 128), blk, 0, stream>>>(
            A, lda, B, ldb, C, ldc, nullptr, nullptr, 0, M, N, K);
    };
    // out-projection: f32 out = A@B + bias + res
    auto outproj = [&](const bf16* A, int lda, const float* B,
                       const float* bias, const float* res, int K) {
        gemm_mfma<1><<<dim3(DIM / 128, ROWS / 128), blk, 0, stream>>>(
            A, lda, B, DIM, out, DIM, bias, res, DIM, ROWS, DIM, K);
    };

    // ---- attn1: sparse-causal self-attention ----
    ln_kernel<<<dim3(ROWS), blk, 0, stream>>>(hs, n1w, n1b, nh);
    proj(nh, DIM, a1wq, DIM, qb, DIM, ROWS, DIM, DIM);
    proj(nh, DIM, a1wk, DIM, kb, DIM, ROWS, DIM, DIM);
    proj(nh, DIM, a1wv, DIM, vb, DIM, ROWS, DIM, DIM);
    attn1_kernel<<<dim3(TOK, HEADS, BF), blk, 0, stream>>>(qb, kb, vb, ob);
    outproj(ob, DIM, a1wo, a1bo, hs, DIM);

    // ---- attn2: cross-attention ----
    ln_kernel<<<dim3(ROWS), blk, 0, stream>>>(out, n2w, n2b, nh);
    proj(nh, DIM, a2wq, DIM, qb, DIM, ROWS, DIM, DIM);
    gemm_valu<<<dim3(DIM / 64, (EROWS + 63) / 64), blk, 0, stream>>>(enc, CROSS, a2wk, DIM, kb, DIM, EROWS, DIM, CROSS);
    gemm_valu<<<dim3(DIM / 64, (EROWS + 63) / 64), blk, 0, stream>>>(enc, CROSS, a2wv, DIM, vb, DIM, EROWS, DIM, CROSS);
    attn2_kernel<<<dim3(TOK, HEADS, BF), blk, 0, stream>>>(qb, kb, vb, ob);
    outproj(ob, DIM, a2wo, a2bo, out, DIM);

    // ---- geglu FFN ----
    ln_kernel<<<dim3(ROWS), blk, 0, stream>>>(out, n3w, n3b, nh);
    gemm_mfma<2><<<dim3(INNER / 128, ROWS / 128), blk, 0, stream>>>(
        nh, DIM, ffw1, 2 * INNER, Pb, INNER, ffb1, nullptr, 0, ROWS, INNER, DIM);
    outproj(Pb, INNER, ffw2, ffb2, out, INNER);

    // ---- temporal self-attention ----
    ln_kernel<<<dim3(ROWS), blk, 0, stream>>>(out, ntw, ntb, nh);
    proj(nh, DIM, atwq, DIM, qb, DIM, ROWS, DIM, DIM);
    proj(nh, DIM, atwk, DIM, kb, DIM, ROWS, DIM, DIM);
    proj(nh, DIM, atwv, DIM, vb, DIM, ROWS, DIM, DIM);
    attnt_kernel<<<dim3(FRAMES, HEADS, BATCH * TOK), blk, 0, stream>>>(qb, kb, vb, ob);
    outproj(ob, DIM, atwo, atbo, out, DIM);
}